// Round 8
// baseline (186.534 us; speedup 1.0000x reference)
//
#include <hip/hip_runtime.h>
#include <hip/hip_bf16.h>
#include <cstdint>

typedef __bf16 bf16x8 __attribute__((ext_vector_type(8)));
typedef __bf16 bf16x2 __attribute__((ext_vector_type(2)));
typedef float f32x4 __attribute__((ext_vector_type(4)));
typedef float f32x2 __attribute__((ext_vector_type(2)));

#define E_DIM 256
#define H_DIM 512

// packed f32x2 -> bf16x2 (RNE): lowers to v_cvt_pk_bf16_f32 on gfx950
static __device__ __forceinline__ unsigned pkbf(float a, float b) {
    bf16x2 h;
    h[0] = (__bf16)a;
    h[1] = (__bf16)b;
    return __builtin_bit_cast(unsigned, h);
}

// ---------------- kernel 1: fused prep, v2 (UNCHANGED from round 7) ----------------
// 512 uniform blocks = (mat 2) x (rowgroup-of-16 64) x (h-quarter 4).
__global__ __launch_bounds__(512, 2)
void prep_kernel(const float* __restrict__ track, const float* __restrict__ det,
                 const float* __restrict__ W1, const float* __restrict__ b1,
                 float* __restrict__ P, float* __restrict__ Q,
                 __bf16* __restrict__ W1cc, float* __restrict__ sclT,
                 float* __restrict__ sclD, float* __restrict__ out) {
    __shared__ __align__(16) __bf16 Ash[16 * 256];   // 8 KB
    int tid  = threadIdx.x;
    int blk  = blockIdx.x;            // 0..511
    int lane = tid & 63;
    int wave = tid >> 6;
    int lq   = lane >> 4;
    int lc   = lane & 15;
    int l5   = lane & 31;

    int mat  = blk >> 8;              // 0 = P(track), 1 = Q(det)
    int rowg = (blk >> 2) & 63;
    int hq   = blk & 3;
    int r0   = rowg * 16;
    int h0   = hq * 128;
    const float* src = mat ? det : track;

    // ---- scattered side jobs (before barrier; overlap with norm phase)
    if (tid < 32) {
        // W1c -> bf16 chunk-major: 32 of 16384 uint4 per block
        int u = blk * 32 + tid;
        int j = u & 3;
        int h = (u >> 2) & 511;
        int c = u >> 11;                              // 0..7
        const float* s = W1 + (size_t)(512 + c * 32 + j * 8) * H_DIM + h;
        uint4 v;
        v.x = pkbf(s[0],                 s[(size_t)1 * H_DIM]);
        v.y = pkbf(s[(size_t)2 * H_DIM], s[(size_t)3 * H_DIM]);
        v.z = pkbf(s[(size_t)4 * H_DIM], s[(size_t)5 * H_DIM]);
        v.w = pkbf(s[(size_t)6 * H_DIM], s[(size_t)7 * H_DIM]);
        *(uint4*)(W1cc + ((size_t)(c * 512 + h) * 32 + j * 8)) = v;
    } else if (tid < 96) {
        // zero 'out' for main's global-atomic accumulation: 64 float4 per block
        float4 z = {0.f, 0.f, 0.f, 0.f};
        ((float4*)out)[blk * 64 + (tid - 32)] = z;
    }

    // ---- load 2 rows per wave, normalize in-register, write Ash + scales
    {
        int row = wave * 2 + (lane >> 5);           // 0..15
        const float* gp = src + (size_t)(r0 + row) * E_DIM + l5 * 8;
        float4 x0 = *(const float4*)gp;
        float4 x1 = *(const float4*)(gp + 4);
        float ss = x0.x*x0.x + x0.y*x0.y + x0.z*x0.z + x0.w*x0.w
                 + x1.x*x1.x + x1.y*x1.y + x1.z*x1.z + x1.w*x1.w;
#pragma unroll
        for (int off = 16; off > 0; off >>= 1) ss += __shfl_xor(ss, off);   // 32-lane groups
        float st = 1.0f / fmaxf(sqrtf(ss), 1e-12f);
        if (hq == 0 && l5 == 0) (mat ? sclD : sclT)[r0 + row] = st;
        uint4 v;
        v.x = pkbf(x0.x * st, x0.y * st);
        v.y = pkbf(x0.z * st, x0.w * st);
        v.z = pkbf(x1.x * st, x1.y * st);
        v.w = pkbf(x1.z * st, x1.w * st);
        int cc = l5 >> 2, j = l5 & 3;               // chunk, k-subgroup
        *(uint4*)&Ash[(size_t)(cc * 64 + j * 16 + row) * 8] = v;
    }
    __syncthreads();

    // ---- K-loop: one 16-h W fragment per wave, gathered f32 from L2, cvt inline
    int hB = h0 + wave * 16 + lc;
    const float* wb = W1 + (size_t)(mat * 256) * H_DIM + hB;
    float wf[8];
#pragma unroll
    for (int i = 0; i < 8; ++i)
        wf[i] = wb[(size_t)(lq * 8 + i) * H_DIM];

    f32x4 acc = (f32x4){0.f, 0.f, 0.f, 0.f};

#pragma unroll
    for (int c = 0; c < 8; ++c) {
        uint4 u;
        u.x = pkbf(wf[0], wf[1]);
        u.y = pkbf(wf[2], wf[3]);
        u.z = pkbf(wf[4], wf[5]);
        u.w = pkbf(wf[6], wf[7]);
        bf16x8 cw = __builtin_bit_cast(bf16x8, u);
        if (c < 7) {
            const float* nb = wb + (size_t)((c + 1) * 32 + lq * 8) * H_DIM;
#pragma unroll
            for (int i = 0; i < 8; ++i)
                wf[i] = nb[(size_t)i * H_DIM];
        }
        bf16x8 af = *(const bf16x8*)&Ash[(size_t)(c * 64 + lane) * 8];
        acc = __builtin_amdgcn_mfma_f32_16x16x32_bf16(cw, af, acc, 0, 0, 0);
    }

    float* dst = mat ? Q : P;
    int h = h0 + wave * 16 + lq * 4;
    f32x4 o = acc;
    if (!mat) o += *(const f32x4*)&b1[h];
    *(f32x4*)&dst[(size_t)(r0 + lc) * H_DIM + h] = o;
}

// ---------------- kernel 2: fused pairwise GEMM + LN + SiLU + W2 dot ----------------
// Round-8: 1024 blocks x 512 thr, each processing TWO adjacent m-tiles with the
// round-5/7 proven memory structure (L2 C-init, no slabs, no DMA). Tile-1 reuses
// the W chunk-0 the ping-pong already loads at c=7 (previously wasted), the same
// P rows / t rows (L1-hot), LDS params, and the launch prologue. A-stage(1) is
// slotted into the stats phase (Ash provably free after B2); C-init(1) follows
// epilogue(0). Barriers per 2 tiles: 7 -> 5. Full prologues per CU: 8 -> 4.
#define A_STAGE(GM)                                                                     \
    {                                                                                   \
        int k0 = wave * 32 + lq * 8;                                                    \
        float sd = sclD[(GM) + ml];                                                     \
        const float* drp = det + (size_t)((GM) + ml) * E_DIM + k0;                      \
        float4 d0 = *(const float4*)drp;                                                \
        float4 d1 = *(const float4*)(drp + 4);                                          \
        _Pragma("unroll")                                                               \
        for (int r = 0; r < 4; ++r) {                                                   \
            int nl = r * 2 + (lc >> 3);                                                 \
            float st = sclT[gn + nl];                                                   \
            const float* trp = track + (size_t)(gn + nl) * E_DIM + k0;                  \
            float4 t0 = *(const float4*)trp;                                            \
            float4 t1 = *(const float4*)(trp + 4);                                      \
            uint4 vv;                                                                   \
            vv.x = pkbf(fabsf(t0.x * st - d0.x * sd), fabsf(t0.y * st - d0.y * sd));    \
            vv.y = pkbf(fabsf(t0.z * st - d0.z * sd), fabsf(t0.w * st - d0.w * sd));    \
            vv.z = pkbf(fabsf(t1.x * st - d1.x * sd), fabsf(t1.y * st - d1.y * sd));    \
            vv.w = pkbf(fabsf(t1.z * st - d1.z * sd), fabsf(t1.w * st - d1.w * sd));    \
            *(uint4*)&Ash[(size_t)(r * 512 + wave * 64 + lane) * 8] = vv;               \
        }                                                                               \
    }

#define C_INIT(GM)                                                                      \
    {                                                                                   \
        const float* Qb = Q + (size_t)(GM) * H_DIM;                                     \
        f32x4 qv[4];                                                                    \
        _Pragma("unroll")                                                               \
        for (int ht = 0; ht < 4; ++ht)                                                  \
            qv[ht] = *(const f32x4*)&Qb[(size_t)ml * H_DIM + wave * 64 + ht * 16 + lq * 4]; \
        _Pragma("unroll")                                                               \
        for (int pt = 0; pt < 4; ++pt) {                                                \
            int n = pt * 2 + (lc >> 3);                                                 \
            _Pragma("unroll")                                                           \
            for (int ht = 0; ht < 4; ++ht) {                                            \
                f32x4 pv = *(const f32x4*)&Pb[(size_t)n * H_DIM + wave * 64 + ht * 16 + lq * 4]; \
                acc[pt][ht] = pv + qv[ht];                                              \
            }                                                                           \
        }                                                                               \
    }

__global__ __launch_bounds__(512, 4)
void main_kernel(const float* __restrict__ track, const float* __restrict__ det,
                 const __bf16* __restrict__ W1cc,
                 const float* __restrict__ P, const float* __restrict__ Q,
                 const float* __restrict__ sclT, const float* __restrict__ sclD,
                 const float* __restrict__ gamma, const float* __restrict__ beta,
                 const float* __restrict__ W2, const float* __restrict__ b2,
                 float* __restrict__ out) {
    __shared__ __align__(16) char SMEM[44032];
    __bf16* Ash  = (__bf16*)SMEM;                     // [0,32768)
    float*  LNr1 = (float*)(SMEM + 32768);            // [64][9]
    float*  LNr2 = (float*)(SMEM + 35072);            // [64][9]
    float*  AS   = (float*)(SMEM + 37376);            // [64]  a = rs
    float*  BS   = (float*)(SMEM + 37632);            // [64]  b = -mu*rs
    float*  Gs   = (float*)(SMEM + 37888);            // [512]
    float*  Bs   = (float*)(SMEM + 39936);            // [512]
    float*  Ws   = (float*)(SMEM + 41984);            // [512]

    int tid  = threadIdx.x;
    int lane = tid & 63;
    int wave = tid >> 6;
    int lq   = lane >> 4;
    int lc   = lane & 15;
    int ml   = lane & 7;

    // ---- XCD swizzle: XCD x owns 4 n-tiles x 4 m-tile-PAIRS per batch
    int i   = blockIdx.x;              // 0..1023
    int xcd = i & 7;
    int t4  = (i >> 3) & 15;
    int b   = i >> 7;
    int n0  = ((xcd >> 1) * 4 + (t4 >> 2)) * 8;
    int mp0 = ((xcd & 1) * 4 + (t4 & 3)) * 16;        // base m of the tile pair
    int gn  = b * 128 + n0;
    int gm0 = b * 128 + mp0;

    float b2v = b2[0];
    Gs[tid] = gamma[tid];
    Bs[tid] = beta[tid];
    Ws[tid] = W2[tid];

    // ---- W1c frags, chunk-0 prefetch (ping-pong re-creates chunk 0 at c=7 for tile 1)
    const uint4* Wg = (const uint4*)W1cc;
    int hb = wave * 64 + lc;
    bf16x8 bwA[4], bwB[4];
#pragma unroll
    for (int ht = 0; ht < 4; ++ht)
        bwA[ht] = __builtin_bit_cast(bf16x8, Wg[(hb + ht * 16) * 4 + lq]);

    const float* Pb = P + (size_t)gn * H_DIM;
    f32x4 acc[4][4];

    // ---- tile 0: stage + C-init
    A_STAGE(gm0)
    C_INIT(gm0)
    __syncthreads();                                   // B1: Ash(0) ready

#pragma unroll 1
    for (int j = 0; j < 2; ++j) {
        // ---- K-loop: zero barriers; unroll-2 ping-pong dbuf; setprio around MFMA
#pragma unroll 2
        for (int c = 0; c < 8; ++c) {
            bf16x8* cur = (c & 1) ? bwB : bwA;
            bf16x8* nxt = (c & 1) ? bwA : bwB;
            int c1 = (c + 1) & 7;
#pragma unroll
            for (int ht = 0; ht < 4; ++ht)
                nxt[ht] = __builtin_bit_cast(bf16x8, Wg[c1 * 2048 + (hb + ht * 16) * 4 + lq]);
            __builtin_amdgcn_s_setprio(1);
#pragma unroll
            for (int pt = 0; pt < 4; ++pt) {
                bf16x8 af = *(const bf16x8*)&Ash[(size_t)((pt * 8 + c) * 64 + lane) * 8];
#pragma unroll
                for (int ht = 0; ht < 4; ++ht)
                    acc[pt][ht] = __builtin_amdgcn_mfma_f32_16x16x32_bf16(cur[ht], af, acc[pt][ht], 0, 0, 0);
            }
            __builtin_amdgcn_s_setprio(0);
        }

        // ---- LN partials: packed f32x2 sums, 2 shuffles, two-stage LDS reduce
#pragma unroll
        for (int pt = 0; pt < 4; ++pt) {
            f32x2 s1v = (f32x2){0.f, 0.f}, s2v = (f32x2){0.f, 0.f};
#pragma unroll
            for (int ht = 0; ht < 4; ++ht) {
#pragma unroll
                for (int hf = 0; hf < 2; ++hf) {
                    f32x2 v = (f32x2){acc[pt][ht][hf * 2], acc[pt][ht][hf * 2 + 1]};
                    s1v += v;
                    s2v += v * v;
                }
            }
            float s1 = s1v[0] + s1v[1];
            float s2 = s2v[0] + s2v[1];
            s1 += __shfl_xor(s1, 16); s2 += __shfl_xor(s2, 16);
            s1 += __shfl_xor(s1, 32); s2 += __shfl_xor(s2, 32);
            if (lq == 0) {
                LNr1[(pt * 16 + lc) * 9 + wave] = s1;
                LNr2[(pt * 16 + lc) * 9 + wave] = s2;
            }
        }
        __syncthreads();                               // B2: K-loop(j) done everywhere
        // ---- stats (all 512 threads) ∥ A-stage for tile 1 (Ash free after B2)
        {
            int p = tid >> 3, w = tid & 7;
            float s1 = LNr1[p * 9 + w];
            float s2 = LNr2[p * 9 + w];
            s1 += __shfl_xor(s1, 1); s2 += __shfl_xor(s2, 1);
            s1 += __shfl_xor(s1, 2); s2 += __shfl_xor(s2, 2);
            s1 += __shfl_xor(s1, 4); s2 += __shfl_xor(s2, 4);
            if (w == 0) {
                float mu  = s1 * (1.0f / 512.0f);
                float var = s2 * (1.0f / 512.0f) - mu * mu;
                float rs  = rsqrtf(var + 1e-5f);
                AS[p] = rs;
                BS[p] = -mu * rs;
            }
        }
        if (j == 0) {
            A_STAGE(gm0 + 8)                           // overlaps stats phase
        }
        __syncthreads();                               // B3: AS/BS + (j==0: Ash(1)) ready

        // ---- epilogue: x = (v*a + b)*g + beta; SiLU; W2 dot; packed f32x2 chain
        float as[4], bs[4];
#pragma unroll
        for (int pt = 0; pt < 4; ++pt) { as[pt] = AS[pt * 16 + lc]; bs[pt] = BS[pt * 16 + lc]; }
        f32x2 cav[4];
#pragma unroll
        for (int pt = 0; pt < 4; ++pt) cav[pt] = (f32x2){0.f, 0.f};
#pragma unroll
        for (int ht = 0; ht < 4; ++ht) {
            int h = wave * 64 + ht * 16 + lq * 4;
            f32x4 g  = *(const f32x4*)&Gs[h];
            f32x4 bb = *(const f32x4*)&Bs[h];
            f32x4 w  = *(const f32x4*)&Ws[h];
#pragma unroll
            for (int pt = 0; pt < 4; ++pt) {
                f32x2 a2  = (f32x2){as[pt], as[pt]};
                f32x2 b2p = (f32x2){bs[pt], bs[pt]};
#pragma unroll
                for (int hf = 0; hf < 2; ++hf) {
                    f32x2 v  = (f32x2){acc[pt][ht][hf * 2], acc[pt][ht][hf * 2 + 1]};
                    f32x2 gg = (f32x2){g[hf * 2],  g[hf * 2 + 1]};
                    f32x2 bv = (f32x2){bb[hf * 2], bb[hf * 2 + 1]};
                    f32x2 wv = (f32x2){w[hf * 2],  w[hf * 2 + 1]};
                    f32x2 x  = (v * a2 + b2p) * gg + bv;
                    f32x2 xw = x * wv;
                    f32x2 e, sg;
                    e[0]  = __expf(-x[0]);
                    e[1]  = __expf(-x[1]);
                    sg[0] = __builtin_amdgcn_rcpf(1.0f + e[0]);
                    sg[1] = __builtin_amdgcn_rcpf(1.0f + e[1]);
                    cav[pt] += xw * sg;
                }
            }
        }
        // ---- output: per-wave partial -> fire-and-forget global atomic
#pragma unroll
        for (int pt = 0; pt < 4; ++pt) {
            float cg = cav[pt][0] + cav[pt][1];
            cg += __shfl_xor(cg, 16);
            cg += __shfl_xor(cg, 32);
            if (lq == 0) {
                if (wave == 0) cg += b2v;              // fold bias once per tile
                int n = pt * 2 + (lc >> 3);
                int m = lc & 7;
                atomicAdd(&out[(size_t)(gn + n) * 128 + mp0 + j * 8 + m], cg);
            }
        }
        // ---- C-init for tile 1 (acc(0) dead after epilogue; Ash(1) already staged)
        if (j == 0) {
            C_INIT(gm0 + 8)
        }
    }
}

extern "C" void kernel_launch(void* const* d_in, const int* in_sizes, int n_in,
                              void* d_out, int out_size, void* d_ws, size_t ws_size,
                              hipStream_t stream) {
    const float* track = (const float*)d_in[0];
    const float* det   = (const float*)d_in[1];
    const float* W1    = (const float*)d_in[2];
    const float* b1    = (const float*)d_in[3];
    const float* gamma = (const float*)d_in[4];
    const float* beta  = (const float*)d_in[5];
    const float* W2    = (const float*)d_in[6];
    const float* b2    = (const float*)d_in[7];
    float* out = (float*)d_out;

    char* ws = (char*)d_ws;
    float*  Pp   = (float*)(ws);                              // 2 MB (1024 x 512 f32)
    float*  Qp   = (float*)(ws + (2u << 20));                 // 2 MB
    __bf16* W1cc = (__bf16*)(ws + (4u << 20));                // 256 KB (mat 2 only)
    float*  sclT = (float*)(ws + (4u << 20) + (256u << 10));  // 4 KB
    float*  sclD = (float*)(ws + (4u << 20) + (264u << 10));  // 4 KB

    prep_kernel<<<512, 512, 0, stream>>>(track, det, W1, b1, Pp, Qp, W1cc, sclT, sclD, out);
    main_kernel<<<1024, 512, 0, stream>>>(track, det, W1cc, Pp, Qp, sclT, sclD,
                                          gamma, beta, W2, b2, out);
}

// Round 10
// 142.537 us; speedup vs baseline: 1.3087x; 1.3087x over previous
//
#include <hip/hip_runtime.h>
#include <hip/hip_bf16.h>
#include <cstdint>

typedef __bf16 bf16x8 __attribute__((ext_vector_type(8)));
typedef __bf16 bf16x2 __attribute__((ext_vector_type(2)));
typedef float f32x4 __attribute__((ext_vector_type(4)));
typedef float f32x2 __attribute__((ext_vector_type(2)));

#define E_DIM 256
#define H_DIM 512

// packed f32x2 -> bf16x2 (RNE): lowers to v_cvt_pk_bf16_f32 on gfx950
static __device__ __forceinline__ unsigned pkbf(float a, float b) {
    bf16x2 h;
    h[0] = (__bf16)a;
    h[1] = (__bf16)b;
    return __builtin_bit_cast(unsigned, h);
}

// ---------------- kernel 1: fused prep, v2 ----------------
// 512 uniform blocks = (mat 2) x (rowgroup-of-16 64) x (h-quarter 4).
// Per block: [prologue side jobs: W1c->bf16 conv (threads 0-31) + out-zeroing
// (threads 32-95), overlapped with row-load+norm] -> barrier -> 8-chunk K-loop
// with one 16-h W fragment per wave (depth-1 prefetch, inline f32->bf16 cvt)
// -> 1 MFMA/chunk -> store P/Q slice.
__global__ __launch_bounds__(512, 2)
void prep_kernel(const float* __restrict__ track, const float* __restrict__ det,
                 const float* __restrict__ W1, const float* __restrict__ b1,
                 float* __restrict__ P, float* __restrict__ Q,
                 __bf16* __restrict__ W1cc, float* __restrict__ sclT,
                 float* __restrict__ sclD, float* __restrict__ out) {
    __shared__ __align__(16) __bf16 Ash[16 * 256];   // 8 KB
    int tid  = threadIdx.x;
    int blk  = blockIdx.x;            // 0..511
    int lane = tid & 63;
    int wave = tid >> 6;
    int lq   = lane >> 4;
    int lc   = lane & 15;
    int l5   = lane & 31;

    int mat  = blk >> 8;              // 0 = P(track), 1 = Q(det)
    int rowg = (blk >> 2) & 63;
    int hq   = blk & 3;
    int r0   = rowg * 16;
    int h0   = hq * 128;
    const float* src = mat ? det : track;

    // ---- scattered side jobs (before barrier; overlap with norm phase)
    if (tid < 32) {
        // W1c -> bf16 chunk-major: 32 of 16384 uint4 per block
        int u = blk * 32 + tid;
        int j = u & 3;
        int h = (u >> 2) & 511;
        int c = u >> 11;                              // 0..7
        const float* s = W1 + (size_t)(512 + c * 32 + j * 8) * H_DIM + h;
        uint4 v;
        v.x = pkbf(s[0],                 s[(size_t)1 * H_DIM]);
        v.y = pkbf(s[(size_t)2 * H_DIM], s[(size_t)3 * H_DIM]);
        v.z = pkbf(s[(size_t)4 * H_DIM], s[(size_t)5 * H_DIM]);
        v.w = pkbf(s[(size_t)6 * H_DIM], s[(size_t)7 * H_DIM]);
        *(uint4*)(W1cc + ((size_t)(c * 512 + h) * 32 + j * 8)) = v;
    } else if (tid < 96) {
        // zero 'out' for main's global-atomic accumulation: 64 float4 per block
        float4 z = {0.f, 0.f, 0.f, 0.f};
        ((float4*)out)[blk * 64 + (tid - 32)] = z;
    }

    // ---- load 2 rows per wave, normalize in-register, write Ash + scales
    {
        int row = wave * 2 + (lane >> 5);           // 0..15
        const float* gp = src + (size_t)(r0 + row) * E_DIM + l5 * 8;
        float4 x0 = *(const float4*)gp;
        float4 x1 = *(const float4*)(gp + 4);
        float ss = x0.x*x0.x + x0.y*x0.y + x0.z*x0.z + x0.w*x0.w
                 + x1.x*x1.x + x1.y*x1.y + x1.z*x1.z + x1.w*x1.w;
#pragma unroll
        for (int off = 16; off > 0; off >>= 1) ss += __shfl_xor(ss, off);   // 32-lane groups
        float st = 1.0f / fmaxf(sqrtf(ss), 1e-12f);
        if (hq == 0 && l5 == 0) (mat ? sclD : sclT)[r0 + row] = st;
        uint4 v;
        v.x = pkbf(x0.x * st, x0.y * st);
        v.y = pkbf(x0.z * st, x0.w * st);
        v.z = pkbf(x1.x * st, x1.y * st);
        v.w = pkbf(x1.z * st, x1.w * st);
        int cc = l5 >> 2, j = l5 & 3;               // chunk, k-subgroup
        *(uint4*)&Ash[(size_t)(cc * 64 + j * 16 + row) * 8] = v;
    }
    __syncthreads();

    // ---- K-loop: one 16-h W fragment per wave, gathered f32 from L2, cvt inline
    int hB = h0 + wave * 16 + lc;
    const float* wb = W1 + (size_t)(mat * 256) * H_DIM + hB;
    float wf[8];
#pragma unroll
    for (int i = 0; i < 8; ++i)
        wf[i] = wb[(size_t)(lq * 8 + i) * H_DIM];

    f32x4 acc = (f32x4){0.f, 0.f, 0.f, 0.f};

#pragma unroll
    for (int c = 0; c < 8; ++c) {
        uint4 u;
        u.x = pkbf(wf[0], wf[1]);
        u.y = pkbf(wf[2], wf[3]);
        u.z = pkbf(wf[4], wf[5]);
        u.w = pkbf(wf[6], wf[7]);
        bf16x8 cw = __builtin_bit_cast(bf16x8, u);
        if (c < 7) {
            const float* nb = wb + (size_t)((c + 1) * 32 + lq * 8) * H_DIM;
#pragma unroll
            for (int i = 0; i < 8; ++i)
                wf[i] = nb[(size_t)i * H_DIM];
        }
        bf16x8 af = *(const bf16x8*)&Ash[(size_t)(c * 64 + lane) * 8];
        acc = __builtin_amdgcn_mfma_f32_16x16x32_bf16(cw, af, acc, 0, 0, 0);
    }

    float* dst = mat ? Q : P;
    int h = h0 + wave * 16 + lq * 4;
    f32x4 o = acc;
    if (!mat) o += *(const f32x4*)&b1[h];
    *(f32x4*)&dst[(size_t)(r0 + lc) * H_DIM + h] = o;
}

// ---------------- kernel 2: fused pairwise GEMM + LN + SiLU + W2 dot ----------------
// EXACT round-7 state (session best: main 77.2-77.9 us, total 141.9 us).
// grid 2048 x 512 thr (8 waves). Block: 64 pairs x 512 H; K=256, 8 chunks.
// One tile per block — the 2048-block generation lockstep is load-bearing for
// L2 locality (rounds 6 & 8 proved multi-tile looping thrashes L2: FETCH x9-12).
// XCD-aware swizzle; atomic fire-and-forget output; setprio around MFMA;
// folded LN coefficients; f32x2 packed partials + epilogue.
__global__ __launch_bounds__(512, 4)
void main_kernel(const float* __restrict__ track, const float* __restrict__ det,
                 const __bf16* __restrict__ W1cc,
                 const float* __restrict__ P, const float* __restrict__ Q,
                 const float* __restrict__ sclT, const float* __restrict__ sclD,
                 const float* __restrict__ gamma, const float* __restrict__ beta,
                 const float* __restrict__ W2, const float* __restrict__ b2,
                 float* __restrict__ out) {
    __shared__ __align__(16) char SMEM[44032];
    __bf16* Ash  = (__bf16*)SMEM;                     // [0,32768)
    float*  LNr1 = (float*)(SMEM + 32768);            // [64][9]
    float*  LNr2 = (float*)(SMEM + 35072);            // [64][9]
    float*  AS   = (float*)(SMEM + 37376);            // [64]  a = rs
    float*  BS   = (float*)(SMEM + 37632);            // [64]  b = -mu*rs
    float*  Gs   = (float*)(SMEM + 37888);            // [512]
    float*  Bs   = (float*)(SMEM + 39936);            // [512]
    float*  Ws   = (float*)(SMEM + 41984);            // [512]

    int tid  = threadIdx.x;
    int lane = tid & 63;
    int wave = tid >> 6;
    int lq   = lane >> 4;
    int lc   = lane & 15;

    // ---- XCD-aware swizzle: XCD x owns a 4x8 (n-tile x m-tile) region per batch
    int i   = blockIdx.x;
    int xcd = i & 7;
    int t8  = (i >> 3) & 31;
    int b   = i >> 8;
    int n0  = ((xcd >> 1) * 4 + (t8 >> 3)) * 8;
    int m0  = ((xcd & 1) * 8 + (t8 & 7)) * 8;
    int gn  = b * 128 + n0;
    int gm  = b * 128 + m0;

    float b2v = b2[0];
    Gs[tid] = gamma[tid];
    Bs[tid] = beta[tid];
    Ws[tid] = W2[tid];

    // ---- W1c frags, chunk-0 prefetch
    const uint4* Wg = (const uint4*)W1cc;
    int hb = wave * 64 + lc;
    bf16x8 bwA[4], bwB[4];
#pragma unroll
    for (int ht = 0; ht < 4; ++ht)
        bwA[ht] = __builtin_bit_cast(bf16x8, Wg[(hb + ht * 16) * 4 + lq]);

    // ---- A-stage: |t*st - d*sd| straight from global (L2-hot) -> Ash
    int k0 = wave * 32 + lq * 8;
    int ml = lane & 7;
    float sd = sclD[gm + ml];
    const float* dr = det + (size_t)(gm + ml) * E_DIM + k0;
    float4 d0 = *(const float4*)dr;
    float4 d1 = *(const float4*)(dr + 4);
#pragma unroll
    for (int r = 0; r < 4; ++r) {
        int nl = r * 2 + (lc >> 3);
        float st = sclT[gn + nl];
        const float* tr = track + (size_t)(gn + nl) * E_DIM + k0;
        float4 t0 = *(const float4*)tr;
        float4 t1 = *(const float4*)(tr + 4);
        uint4 v;
        v.x = pkbf(fabsf(t0.x * st - d0.x * sd), fabsf(t0.y * st - d0.y * sd));
        v.y = pkbf(fabsf(t0.z * st - d0.z * sd), fabsf(t0.w * st - d0.w * sd));
        v.z = pkbf(fabsf(t1.x * st - d1.x * sd), fabsf(t1.y * st - d1.y * sd));
        v.w = pkbf(fabsf(t1.z * st - d1.z * sd), fabsf(t1.w * st - d1.w * sd));
        *(uint4*)&Ash[(size_t)(r * 512 + wave * 64 + lane) * 8] = v;
    }

    // ---- C-init: acc = P[n,h] + Q[m,h] (L2-resident) fused into MFMA C
    const float* Pb = P + (size_t)gn * H_DIM;
    const float* Qb = Q + (size_t)gm * H_DIM;
    f32x4 acc[4][4];
    {
        f32x4 qv[4];
#pragma unroll
        for (int ht = 0; ht < 4; ++ht)
            qv[ht] = *(const f32x4*)&Qb[(size_t)ml * H_DIM + wave * 64 + ht * 16 + lq * 4];
#pragma unroll
        for (int pt = 0; pt < 4; ++pt) {
            int n = pt * 2 + (lc >> 3);
#pragma unroll
            for (int ht = 0; ht < 4; ++ht) {
                f32x4 pv = *(const f32x4*)&Pb[(size_t)n * H_DIM + wave * 64 + ht * 16 + lq * 4];
                acc[pt][ht] = pv + qv[ht];
            }
        }
    }
    __syncthreads();

    // ---- K-loop: zero barriers; unroll-2 ping-pong dbuf; setprio around MFMA
#pragma unroll 2
    for (int c = 0; c < 8; ++c) {
        bf16x8* cur = (c & 1) ? bwB : bwA;
        bf16x8* nxt = (c & 1) ? bwA : bwB;
        int c1 = (c + 1) & 7;
#pragma unroll
        for (int ht = 0; ht < 4; ++ht)
            nxt[ht] = __builtin_bit_cast(bf16x8, Wg[c1 * 2048 + (hb + ht * 16) * 4 + lq]);
        __builtin_amdgcn_s_setprio(1);
#pragma unroll
        for (int pt = 0; pt < 4; ++pt) {
            bf16x8 af = *(const bf16x8*)&Ash[(size_t)((pt * 8 + c) * 64 + lane) * 8];
#pragma unroll
            for (int ht = 0; ht < 4; ++ht)
                acc[pt][ht] = __builtin_amdgcn_mfma_f32_16x16x32_bf16(cur[ht], af, acc[pt][ht], 0, 0, 0);
        }
        __builtin_amdgcn_s_setprio(0);
    }

    // ---- LN partials: packed f32x2 sums, 2 shuffles, two-stage LDS reduce
#pragma unroll
    for (int pt = 0; pt < 4; ++pt) {
        f32x2 s1v = (f32x2){0.f, 0.f}, s2v = (f32x2){0.f, 0.f};
#pragma unroll
        for (int ht = 0; ht < 4; ++ht) {
#pragma unroll
            for (int hf = 0; hf < 2; ++hf) {
                f32x2 v = (f32x2){acc[pt][ht][hf * 2], acc[pt][ht][hf * 2 + 1]};
                s1v += v;
                s2v += v * v;
            }
        }
        float s1 = s1v[0] + s1v[1];
        float s2 = s2v[0] + s2v[1];
        s1 += __shfl_xor(s1, 16); s2 += __shfl_xor(s2, 16);
        s1 += __shfl_xor(s1, 32); s2 += __shfl_xor(s2, 32);
        if (lq == 0) {
            LNr1[(pt * 16 + lc) * 9 + wave] = s1;
            LNr2[(pt * 16 + lc) * 9 + wave] = s2;
        }
    }
    __syncthreads();
    // ---- stats: all 512 threads (8 threads per pair, 3-level shuffle); folded coeffs
    {
        int p = tid >> 3, w = tid & 7;
        float s1 = LNr1[p * 9 + w];
        float s2 = LNr2[p * 9 + w];
        s1 += __shfl_xor(s1, 1); s2 += __shfl_xor(s2, 1);
        s1 += __shfl_xor(s1, 2); s2 += __shfl_xor(s2, 2);
        s1 += __shfl_xor(s1, 4); s2 += __shfl_xor(s2, 4);
        if (w == 0) {
            float mu  = s1 * (1.0f / 512.0f);
            float var = s2 * (1.0f / 512.0f) - mu * mu;
            float rs  = rsqrtf(var + 1e-5f);
            AS[p] = rs;
            BS[p] = -mu * rs;
        }
    }
    __syncthreads();

    // ---- epilogue: x = (v*a + b)*g + beta; SiLU; W2 dot; packed f32x2 chain
    float as[4], bs[4];
#pragma unroll
    for (int pt = 0; pt < 4; ++pt) { as[pt] = AS[pt * 16 + lc]; bs[pt] = BS[pt * 16 + lc]; }
    f32x2 cav[4];
#pragma unroll
    for (int pt = 0; pt < 4; ++pt) cav[pt] = (f32x2){0.f, 0.f};
#pragma unroll
    for (int ht = 0; ht < 4; ++ht) {
        int h = wave * 64 + ht * 16 + lq * 4;
        f32x4 g  = *(const f32x4*)&Gs[h];
        f32x4 bb = *(const f32x4*)&Bs[h];
        f32x4 w  = *(const f32x4*)&Ws[h];
#pragma unroll
        for (int pt = 0; pt < 4; ++pt) {
            f32x2 a2  = (f32x2){as[pt], as[pt]};
            f32x2 b2p = (f32x2){bs[pt], bs[pt]};
#pragma unroll
            for (int hf = 0; hf < 2; ++hf) {
                f32x2 v  = (f32x2){acc[pt][ht][hf * 2], acc[pt][ht][hf * 2 + 1]};
                f32x2 gg = (f32x2){g[hf * 2],  g[hf * 2 + 1]};
                f32x2 bv = (f32x2){bb[hf * 2], bb[hf * 2 + 1]};
                f32x2 wv = (f32x2){w[hf * 2],  w[hf * 2 + 1]};
                f32x2 x  = (v * a2 + b2p) * gg + bv;
                f32x2 xw = x * wv;
                f32x2 e, sg;
                e[0]  = __expf(-x[0]);
                e[1]  = __expf(-x[1]);
                sg[0] = __builtin_amdgcn_rcpf(1.0f + e[0]);
                sg[1] = __builtin_amdgcn_rcpf(1.0f + e[1]);
                cav[pt] += xw * sg;
            }
        }
    }
    // ---- output: per-wave partial -> fire-and-forget global atomic (no barrier,
    // no tail phase; block owns its 64 outputs exclusively, 8-way contention max)
#pragma unroll
    for (int pt = 0; pt < 4; ++pt) {
        float cg = cav[pt][0] + cav[pt][1];
        cg += __shfl_xor(cg, 16);
        cg += __shfl_xor(cg, 32);
        if (lq == 0) {
            if (wave == 0) cg += b2v;               // fold bias exactly once
            int n = pt * 2 + (lc >> 3);
            int m = lc & 7;
            atomicAdd(&out[(size_t)(gn + n) * 128 + m0 + m], cg);
        }
    }
}

extern "C" void kernel_launch(void* const* d_in, const int* in_sizes, int n_in,
                              void* d_out, int out_size, void* d_ws, size_t ws_size,
                              hipStream_t stream) {
    const float* track = (const float*)d_in[0];
    const float* det   = (const float*)d_in[1];
    const float* W1    = (const float*)d_in[2];
    const float* b1    = (const float*)d_in[3];
    const float* gamma = (const float*)d_in[4];
    const float* beta  = (const float*)d_in[5];
    const float* W2    = (const float*)d_in[6];
    const float* b2    = (const float*)d_in[7];
    float* out = (float*)d_out;

    char* ws = (char*)d_ws;
    float*  Pp   = (float*)(ws);                              // 2 MB (1024 x 512 f32)
    float*  Qp   = (float*)(ws + (2u << 20));                 // 2 MB
    __bf16* W1cc = (__bf16*)(ws + (4u << 20));                // 256 KB (mat 2 only)
    float*  sclT = (float*)(ws + (4u << 20) + (256u << 10));  // 4 KB
    float*  sclD = (float*)(ws + (4u << 20) + (264u << 10));  // 4 KB

    prep_kernel<<<512, 512, 0, stream>>>(track, det, W1, b1, Pp, Qp, W1cc, sclT, sclD, out);
    main_kernel<<<2048, 512, 0, stream>>>(track, det, W1cc, Pp, Qp, sclT, sclD,
                                          gamma, beta, W2, b2, out);
}